// Round 6
// baseline (411.443 us; speedup 1.0000x reference)
//
#include <hip/hip_runtime.h>

#define BLK 256
#define ACH 4096   // edges per block in bin passes

// broadcast lane l of v across the wave (l wave-uniform; dynamic is legal)
__device__ __forceinline__ float bcast(float v, int l) {
    return __int_as_float(__builtin_amdgcn_readlane(__float_as_int(v), l));
}
// fp32 <-> bf16 (round-to-nearest-even)
__device__ __forceinline__ unsigned short f2bf(float f) {
    unsigned u = __float_as_uint(f);
    return (unsigned short)((u + 0x7FFFu + ((u >> 16) & 1u)) >> 16);
}
__device__ __forceinline__ float bf2f(unsigned short b) {
    return __uint_as_float(((unsigned)b) << 16);
}

// ---------------- MFMA fragment types ------
typedef __attribute__((ext_vector_type(8))) short bf16x8;
typedef __attribute__((ext_vector_type(4))) float f32x4;

// split 8 fp32 (scaled) into hi/lo bf16 fragments: v ~= hi + lo
__device__ __forceinline__ void split8s(const float* p, float s, bf16x8& h, bf16x8& l) {
    #pragma unroll
    for (int j = 0; j < 8; j++) {
        float v = p[j] * s;
        unsigned short hb = f2bf(v);
        h[j] = (short)hb;
        l[j] = (short)f2bf(v - bf2f(hb));
    }
}
// gather W[kbase+j][col] (stride-64 fp32), split hi/lo
__device__ __forceinline__ void loadWsplit(const float* W, int kbase, int col,
                                           bf16x8& h, bf16x8& l) {
    #pragma unroll
    for (int j = 0; j < 8; j++) {
        float v = W[(size_t)(kbase + j) * 64 + col];
        unsigned short hb = f2bf(v);
        h[j] = (short)hb;
        l[j] = (short)f2bf(v - bf2f(hb));
    }
}

// ================= atomic-free CSR build (two-level binned counting sort) ====

__global__ void k_binA1(const int* __restrict__ vd, const int* __restrict__ hd,
                        const int* __restrict__ id_, const int* __restrict__ sd,
                        int* __restrict__ Tv, int* __restrict__ Th,
                        int* __restrict__ Ti, int* __restrict__ Ts,
                        int ncv, int nch, int nci, int ncs,
                        int nbv_, int nbs_, int Ev, int Eh, int Ei, int Es) {
    __shared__ int cnt[512];
    int blk = blockIdx.x, t = threadIdx.x;
    const int* dd; int* T; int c, nc, nb, E, sf;
    if (blk < ncv)                 { dd = vd;  T = Tv; c = blk;               nc = ncv; nb = nbv_; E = Ev; sf = 8; }
    else if (blk < ncv + nch)      { dd = hd;  T = Th; c = blk - ncv;         nc = nch; nb = nbs_; E = Eh; sf = 7; }
    else if (blk < ncv + nch + nci){ dd = id_; T = Ti; c = blk - ncv - nch;   nc = nci; nb = nbs_; E = Ei; sf = 7; }
    else                           { dd = sd;  T = Ts; c = blk - ncv - nch - nci; nc = ncs; nb = nbs_; E = Es; sf = 7; }
    cnt[t] = 0; cnt[t + 256] = 0;
    __syncthreads();
    int p0 = c * ACH, p1 = min(E, p0 + ACH);
    for (int p = p0 + t; p < p1; p += 256) atomicAdd(&cnt[dd[p] >> sf], 1);
    __syncthreads();
    for (int b = t; b < nb; b += 256) T[(size_t)b * nc + c] = cnt[b];
}

// 3-level exclusive scan over the 4 concatenated T arrays (in place)
__global__ void k_sb2(int* __restrict__ T, int* __restrict__ bsum,
                      int L0, int L1, int L2, int L3,
                      int nB0, int nB1, int nB2, int nB3) {
    __shared__ int sh[256];
    int blk = blockIdx.x;
    int lb, off, L;
    if (blk < nB0)                  { lb = blk;                 off = 0;            L = L0; }
    else if (blk < nB0 + nB1)       { lb = blk - nB0;           off = L0;           L = L1; }
    else if (blk < nB0 + nB1 + nB2) { lb = blk - nB0 - nB1;     off = L0 + L1;      L = L2; }
    else                            { lb = blk - nB0 - nB1 - nB2; off = L0 + L1 + L2; L = L3; }
    int i = lb * 256 + threadIdx.x;
    int v = (i < L) ? T[off + i] : 0;
    sh[threadIdx.x] = v; __syncthreads();
    for (int o2 = 1; o2 < 256; o2 <<= 1) {
        int tmp = (threadIdx.x >= o2) ? sh[threadIdx.x - o2] : 0;
        __syncthreads();
        sh[threadIdx.x] += tmp; __syncthreads();
    }
    if (i < L) T[off + i] = sh[threadIdx.x] - v;
    if (threadIdx.x == 255) bsum[blk] = sh[255];
}

__global__ void k_st2(int* __restrict__ bsum, int nB0, int nB1, int nB2, int nB3) {
    __shared__ int sh[1024];
    int g = blockIdx.x;
    int off = (g == 0) ? 0 : (g == 1) ? nB0 : (g == 2) ? nB0 + nB1 : nB0 + nB1 + nB2;
    int nb  = (g == 0) ? nB0 : (g == 1) ? nB1 : (g == 2) ? nB2 : nB3;
    int tid = threadIdx.x;
    int v = (tid < nb) ? bsum[off + tid] : 0;
    sh[tid] = v; __syncthreads();
    for (int o2 = 1; o2 < 1024; o2 <<= 1) {
        int t = (tid >= o2) ? sh[tid - o2] : 0;
        __syncthreads();
        sh[tid] += t; __syncthreads();
    }
    if (tid < nb) bsum[off + tid] = sh[tid] - v;
}

__global__ void k_sa2(int* __restrict__ T, const int* __restrict__ bsum,
                      int L0, int L1, int L2, int L3,
                      int nB0, int nB1, int nB2, int nB3) {
    int blk = blockIdx.x;
    int lb, off, L;
    if (blk < nB0)                  { lb = blk;                 off = 0;            L = L0; }
    else if (blk < nB0 + nB1)       { lb = blk - nB0;           off = L0;           L = L1; }
    else if (blk < nB0 + nB1 + nB2) { lb = blk - nB0 - nB1;     off = L0 + L1;      L = L2; }
    else                            { lb = blk - nB0 - nB1 - nB2; off = L0 + L1 + L2; L = L3; }
    int i = lb * 256 + threadIdx.x;
    if (i < L) T[off + i] += bsum[blk];
}

// A2 (no-weight graphs vv/in/ss): register-stage 8 edges/thread, LDS counting
// sort by bin, stream out -> piecewise-contiguous global writes.
__global__ __launch_bounds__(512)
void k_binA2a(const int* __restrict__ vs, const int* __restrict__ vd,
              const int* __restrict__ is_, const int* __restrict__ id_,
              const int* __restrict__ ss_, const int* __restrict__ sd,
              const int* __restrict__ Tv, const int* __restrict__ Ti,
              const int* __restrict__ Ts,
              unsigned* __restrict__ vvbin, unsigned* __restrict__ inbin,
              unsigned* __restrict__ ssbin,
              int ncv, int nci, int ncs, int nbv_, int nbs_,
              int Ev, int Ei, int Es) {
    __shared__ int gbase[512], lscan[512], lcur[512];
    __shared__ unsigned sval[ACH];
    __shared__ int sdst[ACH];
    int blk = blockIdx.x, t = threadIdx.x;
    const int *srcp, *dstp, *T; unsigned* bin; int c, nc, nb, E, sf;
    if (blk < ncv)            { srcp = vs;  dstp = vd;  T = Tv; bin = vvbin; c = blk;             nc = ncv; nb = nbv_; E = Ev; sf = 8; }
    else if (blk < ncv + nci) { srcp = is_; dstp = id_; T = Ti; bin = inbin; c = blk - ncv;       nc = nci; nb = nbs_; E = Ei; sf = 7; }
    else                      { srcp = ss_; dstp = sd;  T = Ts; bin = ssbin; c = blk - ncv - nci; nc = ncs; nb = nbs_; E = Es; sf = 7; }
    int msk = (1 << sf) - 1;
    int p0 = c * ACH, p1 = min(E, p0 + ACH);
    if (t < nb) gbase[t] = T[(size_t)t * nc + c];
    lcur[t] = 0;
    int myS[8], myD[8];
    #pragma unroll
    for (int i = 0; i < 8; i++) {
        int p = p0 + t + i * 512;
        if (p < p1) { myS[i] = srcp[p]; myD[i] = dstp[p]; }
        else myD[i] = -1;
    }
    __syncthreads();
    #pragma unroll
    for (int i = 0; i < 8; i++)
        if (myD[i] >= 0) atomicAdd(&lcur[myD[i] >> sf], 1);
    __syncthreads();
    int v = lcur[t];
    lscan[t] = v;
    __syncthreads();
    for (int off = 1; off < 512; off <<= 1) {
        int tmp = (t >= off) ? lscan[t - off] : 0;
        __syncthreads();
        lscan[t] += tmp;
        __syncthreads();
    }
    int excl = lscan[t] - v;
    __syncthreads();
    lscan[t] = excl;
    lcur[t] = 0;
    __syncthreads();
    #pragma unroll
    for (int i = 0; i < 8; i++) {
        if (myD[i] < 0) continue;
        int b = myD[i] >> sf;
        int r = atomicAdd(&lcur[b], 1);
        int pos = lscan[b] + r;
        sval[pos] = ((unsigned)myS[i] << sf) | (unsigned)(myD[i] & msk);
        sdst[pos] = gbase[b] + r;
    }
    __syncthreads();
    int cntE = p1 - p0;
    for (int q = t; q < cntE; q += 512) bin[sdst[q]] = sval[q];
}

// A2 for the weighted h graph (int2 payload)
__global__ __launch_bounds__(512)
void k_binA2h(const int* __restrict__ hs, const int* __restrict__ hd,
              const float* __restrict__ hw, const int* __restrict__ Th,
              int2* __restrict__ hbin, int nch, int nbs_, int Eh) {
    __shared__ int gbase[512], lscan[512], lcur[512];
    __shared__ unsigned sval[ACH];
    __shared__ int sdst[ACH];
    __shared__ float swt[ACH];
    int c = blockIdx.x, t = threadIdx.x;
    const int sf = 7, msk = 127;
    int p0 = c * ACH, p1 = min(Eh, p0 + ACH);
    if (t < nbs_) gbase[t] = Th[(size_t)t * nch + c];
    lcur[t] = 0;
    int myS[8], myD[8]; float myW[8];
    #pragma unroll
    for (int i = 0; i < 8; i++) {
        int p = p0 + t + i * 512;
        if (p < p1) { myS[i] = hs[p]; myD[i] = hd[p]; myW[i] = hw[p]; }
        else myD[i] = -1;
    }
    __syncthreads();
    #pragma unroll
    for (int i = 0; i < 8; i++)
        if (myD[i] >= 0) atomicAdd(&lcur[myD[i] >> sf], 1);
    __syncthreads();
    int v = lcur[t];
    lscan[t] = v;
    __syncthreads();
    for (int off = 1; off < 512; off <<= 1) {
        int tmp = (t >= off) ? lscan[t - off] : 0;
        __syncthreads();
        lscan[t] += tmp;
        __syncthreads();
    }
    int excl = lscan[t] - v;
    __syncthreads();
    lscan[t] = excl;
    lcur[t] = 0;
    __syncthreads();
    #pragma unroll
    for (int i = 0; i < 8; i++) {
        if (myD[i] < 0) continue;
        int b = myD[i] >> sf;
        int r = atomicAdd(&lcur[b], 1);
        int pos = lscan[b] + r;
        sval[pos] = ((unsigned)myS[i] << sf) | (unsigned)(myD[i] & msk);
        sdst[pos] = gbase[b] + r;
        swt[pos] = myW[i];
    }
    __syncthreads();
    int cntE = p1 - p0;
    for (int q = t; q < cntE; q += 512)
        hbin[sdst[q]] = make_int2((int)sval[q], __float_as_int(swt[q]));
}

// binB: per-bin dst-local hist -> rowptr + dinv + final CSR scatter.
// For the vv graph (g==0) it also emits the packed (x[5], rsqrt(deg)) node
// packet used by the gather5p hops (folds the old k_pack5 kernel).
__global__ void k_binB(const unsigned* __restrict__ vvbin, const int2* __restrict__ hbin,
                       const unsigned* __restrict__ inbin, const unsigned* __restrict__ ssbin,
                       const int* __restrict__ Tv, const int* __restrict__ Th,
                       const int* __restrict__ Ti, const int* __restrict__ Ts,
                       int* __restrict__ rv, int* __restrict__ rh,
                       int* __restrict__ ri, int* __restrict__ rs,
                       const float* __restrict__ gx5, float* __restrict__ P0,
                       float* __restrict__ dinv_s,
                       int* __restrict__ vvsrc, int2* __restrict__ hsw,
                       int* __restrict__ insrc, int* __restrict__ sssrc,
                       int ncv, int nch, int nci, int ncs,
                       int nbv_, int nbs_, int nv, int ns,
                       int Ev, int Eh, int Ei, int Es) {
    __shared__ int cnt[256]; __shared__ int pre[256]; __shared__ int cur[256];
    int blk = blockIdx.x, t = threadIdx.x;
    int g, b, nb, nc, sf, n, E; const int* T; int* rp;
    if (blk < nbv_)                 { g = 0; b = blk;                 nb = nbv_; nc = ncv; sf = 8; n = nv; E = Ev; T = Tv; rp = rv; }
    else if (blk < nbv_ + nbs_)     { g = 1; b = blk - nbv_;          nb = nbs_; nc = nch; sf = 7; n = ns; E = Eh; T = Th; rp = rh; }
    else if (blk < nbv_ + 2 * nbs_) { g = 2; b = blk - nbv_ - nbs_;   nb = nbs_; nc = nci; sf = 7; n = ns; E = Ei; T = Ti; rp = ri; }
    else                            { g = 3; b = blk - nbv_ - 2 * nbs_; nb = nbs_; nc = ncs; sf = 7; n = ns; E = Es; T = Ts; rp = rs; }
    int W = 1 << sf, msk = W - 1;
    int e0 = T[(size_t)b * nc];
    int e1 = (b + 1 < nb) ? T[(size_t)(b + 1) * nc] : E;
    cnt[t] = 0; __syncthreads();
    for (int p = e0 + t; p < e1; p += 256) {
        unsigned pk = (g == 1) ? (unsigned)hbin[p].x
                    : (g == 0) ? vvbin[p] : (g == 2) ? inbin[p] : ssbin[p];
        atomicAdd(&cnt[pk & msk], 1);
    }
    __syncthreads();
    int v = cnt[t];
    pre[t] = v; __syncthreads();
    for (int o2 = 1; o2 < 256; o2 <<= 1) {
        int tmp = (t >= o2) ? pre[t - o2] : 0;
        __syncthreads();
        pre[t] += tmp; __syncthreads();
    }
    int excl = pre[t] - v;
    int d = b * W + t;
    if (t < W && d < n) {
        rp[d] = e0 + excl;
        if (g == 0) {
            const float* xp = gx5 + (size_t)d * 5;
            float di = v > 0 ? rsqrtf((float)v) : 0.f;
            ((float4*)P0)[(size_t)d * 2]     = make_float4(xp[0], xp[1], xp[2], xp[3]);
            ((float4*)P0)[(size_t)d * 2 + 1] = make_float4(xp[4], di, 0.f, 0.f);
        } else if (g == 3) {
            dinv_s[d] = v > 0 ? rsqrtf((float)v) : 0.f;
        }
    }
    cur[t] = e0 + excl;
    __syncthreads();
    for (int p = e0 + t; p < e1; p += 256) {
        if (g == 1) {
            int2 r = hbin[p];
            unsigned pk = (unsigned)r.x;
            int pos = atomicAdd(&cur[pk & msk], 1);
            hsw[pos] = make_int2((int)(pk >> sf), r.y);
        } else {
            unsigned pk = (g == 0) ? vvbin[p] : (g == 2) ? inbin[p] : ssbin[p];
            int pos = atomicAdd(&cur[pk & msk], 1);
            int sv = (int)(pk >> sf);
            if (g == 0)      vvsrc[pos] = sv;
            else if (g == 2) insrc[pos] = sv;
            else             sssrc[pos] = sv;
        }
    }
    if (b == 0 && t == 0) rp[n] = E;
}

// ================= gathers =================

// gather over 32B (x[5],dinv) packets; output is also a packet for the next hop
__global__ void k_gather5p(const float* __restrict__ Pin, const int* __restrict__ rowptr,
                           const int* __restrict__ csr_src, float* __restrict__ Pout, int n) {
    int d = blockIdx.x * blockDim.x + threadIdx.x;
    if (d >= n) return;
    int b = rowptr[d], e = rowptr[d + 1];
    float dd = Pin[(size_t)d * 8 + 5];
    float a0 = 0, a1 = 0, a2 = 0, a3 = 0, a4 = 0;
    int p = b;
    for (; p + 4 <= e; p += 4) {
        int s0 = csr_src[p], s1 = csr_src[p+1], s2 = csr_src[p+2], s3 = csr_src[p+3];
        float4 x0a = ((const float4*)Pin)[(size_t)s0 * 2], x0b = ((const float4*)Pin)[(size_t)s0 * 2 + 1];
        float4 x1a = ((const float4*)Pin)[(size_t)s1 * 2], x1b = ((const float4*)Pin)[(size_t)s1 * 2 + 1];
        float4 x2a = ((const float4*)Pin)[(size_t)s2 * 2], x2b = ((const float4*)Pin)[(size_t)s2 * 2 + 1];
        float4 x3a = ((const float4*)Pin)[(size_t)s3 * 2], x3b = ((const float4*)Pin)[(size_t)s3 * 2 + 1];
        float w0 = dd * x0b.y, w1 = dd * x1b.y, w2 = dd * x2b.y, w3 = dd * x3b.y;
        a0 += x0a.x*w0 + x1a.x*w1 + x2a.x*w2 + x3a.x*w3;
        a1 += x0a.y*w0 + x1a.y*w1 + x2a.y*w2 + x3a.y*w3;
        a2 += x0a.z*w0 + x1a.z*w1 + x2a.z*w2 + x3a.z*w3;
        a3 += x0a.w*w0 + x1a.w*w1 + x2a.w*w2 + x3a.w*w3;
        a4 += x0b.x*w0 + x1b.x*w1 + x2b.x*w2 + x3b.x*w3;
    }
    for (; p < e; p++) {
        int s = csr_src[p];
        float4 xa = ((const float4*)Pin)[(size_t)s * 2], xb = ((const float4*)Pin)[(size_t)s * 2 + 1];
        float w = dd * xb.y;
        a0 += xa.x*w; a1 += xa.y*w; a2 += xa.z*w; a3 += xa.w*w; a4 += xb.x*w;
    }
    ((float4*)Pout)[(size_t)d * 2]     = make_float4(a0, a1, a2, a3);
    ((float4*)Pout)[(size_t)d * 2 + 1] = make_float4(a4, dd, 0.f, 0.f);
}

// Fused stage-B + stage-C gather: wave wid<n does the weighted h-graph row,
// wave wid>=n does the plain in-graph row. Both read gx_bf (shared hot set),
// both write fp32 rows. Doubles resident waves for latency hiding.
__global__ void k_gatherBC(const unsigned short* __restrict__ xbf,
                           const int* __restrict__ rh, const int2* __restrict__ hsw,
                           const int* __restrict__ ri, const int* __restrict__ insrc,
                           float* __restrict__ aggH, float* __restrict__ aggI, int n) {
    int wid = (int)(((long long)blockIdx.x * blockDim.x + threadIdx.x) >> 6);
    if (wid >= 2 * n) return;
    int lane = threadIdx.x & 63;
    int g = lane >> 4, q = lane & 15;
    float4 acc = make_float4(0.f, 0.f, 0.f, 0.f);
    float* outp;
    int row;
    if (wid < n) {
        row = wid;
        int b = rh[row], e = rh[row + 1];
        int p = b + g;
        for (; p + 12 < e; p += 16) {
            int2 e0 = hsw[p], e1 = hsw[p+4], e2 = hsw[p+8], e3 = hsw[p+12];
            float w0 = __int_as_float(e0.y), w1 = __int_as_float(e1.y);
            float w2 = __int_as_float(e2.y), w3 = __int_as_float(e3.y);
            ushort4 u0 = ((const ushort4*)(xbf + (size_t)e0.x * 64))[q];
            ushort4 u1 = ((const ushort4*)(xbf + (size_t)e1.x * 64))[q];
            ushort4 u2 = ((const ushort4*)(xbf + (size_t)e2.x * 64))[q];
            ushort4 u3 = ((const ushort4*)(xbf + (size_t)e3.x * 64))[q];
            acc.x += bf2f(u0.x)*w0 + bf2f(u1.x)*w1 + bf2f(u2.x)*w2 + bf2f(u3.x)*w3;
            acc.y += bf2f(u0.y)*w0 + bf2f(u1.y)*w1 + bf2f(u2.y)*w2 + bf2f(u3.y)*w3;
            acc.z += bf2f(u0.z)*w0 + bf2f(u1.z)*w1 + bf2f(u2.z)*w2 + bf2f(u3.z)*w3;
            acc.w += bf2f(u0.w)*w0 + bf2f(u1.w)*w1 + bf2f(u2.w)*w2 + bf2f(u3.w)*w3;
        }
        for (; p < e; p += 4) {
            int2 e0 = hsw[p];
            float w = __int_as_float(e0.y);
            ushort4 u = ((const ushort4*)(xbf + (size_t)e0.x * 64))[q];
            acc.x += bf2f(u.x)*w; acc.y += bf2f(u.y)*w;
            acc.z += bf2f(u.z)*w; acc.w += bf2f(u.w)*w;
        }
        outp = aggH;
    } else {
        row = wid - n;
        int b = ri[row], e = ri[row + 1];
        int p = b + g;
        for (; p + 12 < e; p += 16) {
            int s0 = insrc[p], s1 = insrc[p+4], s2 = insrc[p+8], s3 = insrc[p+12];
            ushort4 u0 = ((const ushort4*)(xbf + (size_t)s0 * 64))[q];
            ushort4 u1 = ((const ushort4*)(xbf + (size_t)s1 * 64))[q];
            ushort4 u2 = ((const ushort4*)(xbf + (size_t)s2 * 64))[q];
            ushort4 u3 = ((const ushort4*)(xbf + (size_t)s3 * 64))[q];
            acc.x += bf2f(u0.x) + bf2f(u1.x) + bf2f(u2.x) + bf2f(u3.x);
            acc.y += bf2f(u0.y) + bf2f(u1.y) + bf2f(u2.y) + bf2f(u3.y);
            acc.z += bf2f(u0.z) + bf2f(u1.z) + bf2f(u2.z) + bf2f(u3.z);
            acc.w += bf2f(u0.w) + bf2f(u1.w) + bf2f(u2.w) + bf2f(u3.w);
        }
        for (; p < e; p += 4) {
            int s = insrc[p];
            ushort4 u = ((const ushort4*)(xbf + (size_t)s * 64))[q];
            acc.x += bf2f(u.x); acc.y += bf2f(u.y);
            acc.z += bf2f(u.z); acc.w += bf2f(u.w);
        }
        outp = aggI;
    }
    #pragma unroll
    for (int off = 16; off < 64; off <<= 1) {
        acc.x += __shfl_xor(acc.x, off, 64);
        acc.y += __shfl_xor(acc.y, off, 64);
        acc.z += __shfl_xor(acc.z, off, 64);
        acc.w += __shfl_xor(acc.w, off, 64);
    }
    if (g == 0) ((float4*)outp)[(size_t)row * 16 + q] = acc;
}

// 64-ch gather, MODE 2 (symmetric gcn norm), bf16 out — ss-graph hops
template<int MODE, bool OUTBF>
__global__ void k_gather64(const unsigned short* __restrict__ xbf, const int* __restrict__ rowptr,
                           const int* __restrict__ csr_src, const int2* __restrict__ csr_sw,
                           const float* __restrict__ dinv, void* __restrict__ outp, int n) {
    int wid = (int)(((long long)blockIdx.x * blockDim.x + threadIdx.x) >> 6);
    if (wid >= n) return;
    int lane = threadIdx.x & 63;
    int g = lane >> 4, q = lane & 15;
    int b = rowptr[wid], e = rowptr[wid + 1];
    float dd = (MODE == 2) ? dinv[wid] : 0.f;
    float4 acc = make_float4(0.f, 0.f, 0.f, 0.f);
    int p = b + g;
    for (; p + 12 < e; p += 16) {
        int s0, s1, s2, s3;
        float w0 = 1.f, w1 = 1.f, w2 = 1.f, w3 = 1.f;
        if (MODE == 1) {
            int2 e0 = csr_sw[p], e1 = csr_sw[p+4], e2 = csr_sw[p+8], e3 = csr_sw[p+12];
            s0 = e0.x; w0 = __int_as_float(e0.y);
            s1 = e1.x; w1 = __int_as_float(e1.y);
            s2 = e2.x; w2 = __int_as_float(e2.y);
            s3 = e3.x; w3 = __int_as_float(e3.y);
        } else {
            s0 = csr_src[p]; s1 = csr_src[p+4]; s2 = csr_src[p+8]; s3 = csr_src[p+12];
            if (MODE == 2) {
                w0 = dd * dinv[s0]; w1 = dd * dinv[s1];
                w2 = dd * dinv[s2]; w3 = dd * dinv[s3];
            }
        }
        ushort4 u0 = ((const ushort4*)(xbf + (size_t)s0 * 64))[q];
        ushort4 u1 = ((const ushort4*)(xbf + (size_t)s1 * 64))[q];
        ushort4 u2 = ((const ushort4*)(xbf + (size_t)s2 * 64))[q];
        ushort4 u3 = ((const ushort4*)(xbf + (size_t)s3 * 64))[q];
        acc.x += bf2f(u0.x)*w0 + bf2f(u1.x)*w1 + bf2f(u2.x)*w2 + bf2f(u3.x)*w3;
        acc.y += bf2f(u0.y)*w0 + bf2f(u1.y)*w1 + bf2f(u2.y)*w2 + bf2f(u3.y)*w3;
        acc.z += bf2f(u0.z)*w0 + bf2f(u1.z)*w1 + bf2f(u2.z)*w2 + bf2f(u3.z)*w3;
        acc.w += bf2f(u0.w)*w0 + bf2f(u1.w)*w1 + bf2f(u2.w)*w2 + bf2f(u3.w)*w3;
    }
    for (; p < e; p += 4) {
        int s; float w = 1.f;
        if (MODE == 1) { int2 e0 = csr_sw[p]; s = e0.x; w = __int_as_float(e0.y); }
        else { s = csr_src[p]; if (MODE == 2) w = dd * dinv[s]; }
        ushort4 u = ((const ushort4*)(xbf + (size_t)s * 64))[q];
        acc.x += bf2f(u.x)*w; acc.y += bf2f(u.y)*w;
        acc.z += bf2f(u.z)*w; acc.w += bf2f(u.w)*w;
    }
    #pragma unroll
    for (int off = 16; off < 64; off <<= 1) {
        acc.x += __shfl_xor(acc.x, off, 64);
        acc.y += __shfl_xor(acc.y, off, 64);
        acc.z += __shfl_xor(acc.z, off, 64);
        acc.w += __shfl_xor(acc.w, off, 64);
    }
    if (g == 0) {
        if (OUTBF) {
            ushort4 ov;
            ov.x = f2bf(acc.x); ov.y = f2bf(acc.y); ov.z = f2bf(acc.z); ov.w = f2bf(acc.w);
            ((ushort4*)outp)[(size_t)wid * 16 + q] = ov;
        } else {
            ((float4*)outp)[(size_t)wid * 16 + q] = acc;
        }
    }
}

// ============ dense combines (MFMA wave GEMMs, 32 rows x 64 cols/wave) =======
// k-map: A and B both loaded with k = kh*32 + g*8 + j (g = lane>>4, j = elem).
// C/D layout (HW-verified): col = lane&15, row = g*4 + reg.

// Fused GraphConv + SAGE: sx = relu(gb + aggH@Wrel + st@Wroot) stays in LDS;
// out = bf16(relu(sbl + (ssum/max(cnt,1))@Wl + sx@Wr)). No sx global round-trip.
__global__ __launch_bounds__(256)
void k_gcsage_mf(const float* __restrict__ aggH, const float* __restrict__ st,
                 const float* __restrict__ Wrel, const float* __restrict__ Wroot,
                 const float* __restrict__ gb,
                 const float* __restrict__ ssum, const int* __restrict__ ri,
                 const float* __restrict__ Wl, const float* __restrict__ Wr,
                 const float* __restrict__ sbl,
                 unsigned short* __restrict__ out, int n) {
    __shared__ float lds[4][32][64];
    int tid = threadIdx.x;
    int wv = (int)(((long long)blockIdx.x * blockDim.x + tid) >> 6);
    int w = (tid >> 6) & 3;
    int lane = tid & 63;
    int lm = lane & 15, g = lane >> 4;
    int r0 = wv * 32;
    bool active = (r0 < n);
    int r0c = active ? r0 : 0;
    // ---- GraphConv phase: sx -> LDS ----
    {
        bf16x8 axh[2][2], axl[2][2], arh[2], arl[2];
        #pragma unroll
        for (int mt = 0; mt < 2; mt++) {
            int row = r0c + mt * 16 + lm; if (row >= n) row = n - 1;
            #pragma unroll
            for (int kh = 0; kh < 2; kh++)
                split8s(aggH + (size_t)row * 64 + kh * 32 + g * 8, 1.f, axh[mt][kh], axl[mt][kh]);
            #pragma unroll
            for (int j = 0; j < 8; j++) {
                int k = g * 8 + j;
                float v = (k < 6) ? st[(size_t)row * 6 + k] : 0.f;
                unsigned short hb = f2bf(v);
                arh[mt][j] = (short)hb;
                arl[mt][j] = (short)f2bf(v - bf2f(hb));
            }
        }
        #pragma unroll
        for (int nt = 0; nt < 4; nt++) {
            int col = nt * 16 + lm;
            bf16x8 bh[2], blo[2], brh, brl;
            #pragma unroll
            for (int kh = 0; kh < 2; kh++) loadWsplit(Wrel, kh * 32 + g * 8, col, bh[kh], blo[kh]);
            #pragma unroll
            for (int j = 0; j < 8; j++) {
                int k = g * 8 + j;
                float v = (k < 6) ? Wroot[(size_t)k * 64 + col] : 0.f;
                unsigned short hb = f2bf(v);
                brh[j] = (short)hb;
                brl[j] = (short)f2bf(v - bf2f(hb));
            }
            #pragma unroll
            for (int mt = 0; mt < 2; mt++) {
                f32x4 acc = {0.f, 0.f, 0.f, 0.f};
                #pragma unroll
                for (int kh = 0; kh < 2; kh++) {
                    acc = __builtin_amdgcn_mfma_f32_16x16x32_bf16(axh[mt][kh], bh[kh],  acc, 0, 0, 0);
                    acc = __builtin_amdgcn_mfma_f32_16x16x32_bf16(axl[mt][kh], bh[kh],  acc, 0, 0, 0);
                    acc = __builtin_amdgcn_mfma_f32_16x16x32_bf16(axh[mt][kh], blo[kh], acc, 0, 0, 0);
                }
                acc = __builtin_amdgcn_mfma_f32_16x16x32_bf16(arh[mt], brh, acc, 0, 0, 0);
                acc = __builtin_amdgcn_mfma_f32_16x16x32_bf16(arl[mt], brh, acc, 0, 0, 0);
                acc = __builtin_amdgcn_mfma_f32_16x16x32_bf16(arh[mt], brl, acc, 0, 0, 0);
                float bias = gb[col];
                #pragma unroll
                for (int r = 0; r < 4; r++)
                    lds[w][mt * 16 + g * 4 + r][col] = fmaxf(bias + acc[r], 0.f);
            }
        }
    }
    __syncthreads();
    // ---- SAGE phase ----
    {
        bf16x8 mh[2][2], ml[2][2], sh_[2][2], sl_[2][2];
        #pragma unroll
        for (int mt = 0; mt < 2; mt++) {
            int row = r0c + mt * 16 + lm; if (row >= n) row = n - 1;
            float cnt = (float)(ri[row + 1] - ri[row]);
            float rs = 1.f / fmaxf(cnt, 1.f);
            #pragma unroll
            for (int kh = 0; kh < 2; kh++) {
                split8s(ssum + (size_t)row * 64 + kh * 32 + g * 8, rs, mh[mt][kh], ml[mt][kh]);
                #pragma unroll
                for (int j = 0; j < 8; j++) {
                    float v = lds[w][mt * 16 + lm][kh * 32 + g * 8 + j];
                    unsigned short hb = f2bf(v);
                    sh_[mt][kh][j] = (short)hb;
                    sl_[mt][kh][j] = (short)f2bf(v - bf2f(hb));
                }
            }
        }
        #pragma unroll
        for (int nt = 0; nt < 4; nt++) {
            int col = nt * 16 + lm;
            bf16x8 blh[2], bll[2], brh2[2], brl2[2];
            #pragma unroll
            for (int kh = 0; kh < 2; kh++) {
                loadWsplit(Wl, kh * 32 + g * 8, col, blh[kh], bll[kh]);
                loadWsplit(Wr, kh * 32 + g * 8, col, brh2[kh], brl2[kh]);
            }
            #pragma unroll
            for (int mt = 0; mt < 2; mt++) {
                f32x4 acc = {0.f, 0.f, 0.f, 0.f};
                #pragma unroll
                for (int kh = 0; kh < 2; kh++) {
                    acc = __builtin_amdgcn_mfma_f32_16x16x32_bf16(mh[mt][kh],  blh[kh],  acc, 0, 0, 0);
                    acc = __builtin_amdgcn_mfma_f32_16x16x32_bf16(ml[mt][kh],  blh[kh],  acc, 0, 0, 0);
                    acc = __builtin_amdgcn_mfma_f32_16x16x32_bf16(mh[mt][kh],  bll[kh],  acc, 0, 0, 0);
                    acc = __builtin_amdgcn_mfma_f32_16x16x32_bf16(sh_[mt][kh], brh2[kh], acc, 0, 0, 0);
                    acc = __builtin_amdgcn_mfma_f32_16x16x32_bf16(sl_[mt][kh], brh2[kh], acc, 0, 0, 0);
                    acc = __builtin_amdgcn_mfma_f32_16x16x32_bf16(sh_[mt][kh], brl2[kh], acc, 0, 0, 0);
                }
                float bias = sbl[col];
                #pragma unroll
                for (int r = 0; r < 4; r++) {
                    int row = r0 + mt * 16 + g * 4 + r;
                    if (active && row < n)
                        out[(size_t)row * 64 + col] = f2bf(fmaxf(bias + acc[r], 0.f));
                }
            }
        }
    }
}

// Fused TAG2 combine + final linear:
// out8 = lin_b + relu(tag2_b + x0@W0 + x1@W1 + x2@W2 + x3@W3) @ lin_W
__global__ __launch_bounds__(256)
void k_tagmm(const unsigned short* __restrict__ x0, const unsigned short* __restrict__ x1,
             const unsigned short* __restrict__ x2, const unsigned short* __restrict__ x3,
             const float* __restrict__ W4, const float* __restrict__ tb,
             const float* __restrict__ lW, const float* __restrict__ lb,
             float* __restrict__ out, int n) {
    __shared__ float lds[4][32][64];
    int tid = threadIdx.x;
    int wv = (int)(((long long)blockIdx.x * blockDim.x + tid) >> 6);
    int w = (tid >> 6) & 3;
    int lane = tid & 63;
    int lm = lane & 15, g = lane >> 4;
    int r0 = wv * 32;
    bool active = (r0 < n);
    int r0c = active ? r0 : 0;
    const unsigned short* xs[4] = {x0, x1, x2, x3};
    f32x4 acc[2][4];
    #pragma unroll
    for (int mt = 0; mt < 2; mt++)
        #pragma unroll
        for (int nt = 0; nt < 4; nt++) acc[mt][nt] = (f32x4){0.f, 0.f, 0.f, 0.f};
    #pragma unroll
    for (int inp = 0; inp < 4; inp++) {
        const unsigned short* xp = xs[inp];
        const float* W = W4 + inp * 4096;
        bf16x8 a[2][2];
        #pragma unroll
        for (int mt = 0; mt < 2; mt++) {
            int row = r0c + mt * 16 + lm; if (row >= n) row = n - 1;
            #pragma unroll
            for (int kh = 0; kh < 2; kh++)
                a[mt][kh] = *(const bf16x8*)(xp + (size_t)row * 64 + kh * 32 + g * 8);
        }
        #pragma unroll
        for (int nt = 0; nt < 4; nt++) {
            int col = nt * 16 + lm;
            bf16x8 bh[2], blo[2];
            #pragma unroll
            for (int kh = 0; kh < 2; kh++) loadWsplit(W, kh * 32 + g * 8, col, bh[kh], blo[kh]);
            #pragma unroll
            for (int mt = 0; mt < 2; mt++) {
                #pragma unroll
                for (int kh = 0; kh < 2; kh++) {
                    acc[mt][nt] = __builtin_amdgcn_mfma_f32_16x16x32_bf16(a[mt][kh], bh[kh],  acc[mt][nt], 0, 0, 0);
                    acc[mt][nt] = __builtin_amdgcn_mfma_f32_16x16x32_bf16(a[mt][kh], blo[kh], acc[mt][nt], 0, 0, 0);
                }
            }
        }
    }
    #pragma unroll
    for (int mt = 0; mt < 2; mt++)
        #pragma unroll
        for (int nt = 0; nt < 4; nt++) {
            int col = nt * 16 + lm;
            float bias = tb[col];
            #pragma unroll
            for (int r = 0; r < 4; r++)
                lds[w][mt * 16 + g * 4 + r][col] = fmaxf(bias + acc[mt][nt][r], 0.f);
        }
    __syncthreads();
    bf16x8 bh2[2], bl2[2];
    #pragma unroll
    for (int kh = 0; kh < 2; kh++) {
        #pragma unroll
        for (int j = 0; j < 8; j++) {
            int k = kh * 32 + g * 8 + j;
            float v = (lm < 8) ? lW[k * 8 + lm] : 0.f;
            unsigned short hb = f2bf(v);
            bh2[kh][j] = (short)hb;
            bl2[kh][j] = (short)f2bf(v - bf2f(hb));
        }
    }
    #pragma unroll
    for (int mt = 0; mt < 2; mt++) {
        bf16x8 ah[2], al[2];
        #pragma unroll
        for (int kh = 0; kh < 2; kh++) {
            #pragma unroll
            for (int j = 0; j < 8; j++) {
                float v = lds[w][mt * 16 + lm][kh * 32 + g * 8 + j];
                unsigned short hb = f2bf(v);
                ah[kh][j] = (short)hb;
                al[kh][j] = (short)f2bf(v - bf2f(hb));
            }
        }
        f32x4 oacc = {0.f, 0.f, 0.f, 0.f};
        #pragma unroll
        for (int kh = 0; kh < 2; kh++) {
            oacc = __builtin_amdgcn_mfma_f32_16x16x32_bf16(ah[kh], bh2[kh], oacc, 0, 0, 0);
            oacc = __builtin_amdgcn_mfma_f32_16x16x32_bf16(al[kh], bh2[kh], oacc, 0, 0, 0);
            oacc = __builtin_amdgcn_mfma_f32_16x16x32_bf16(ah[kh], bl2[kh], oacc, 0, 0, 0);
        }
        if (lm < 8) {
            #pragma unroll
            for (int r = 0; r < 4; r++) {
                int row = r0 + mt * 16 + g * 4 + r;
                if (active && row < n) out[(size_t)row * 8 + lm] = oacc[r] + lb[lm];
            }
        }
    }
}

// gx_bf = bf16(relu(b + x@W0 + h1@W1 + h2@W2))  (K=5 inputs; VALU is fine)
// h1/h2 are 8-float packets (stride 8)
__global__ __launch_bounds__(256, 4)
void k_tag1_w(const float* __restrict__ x, const float* __restrict__ h1,
              const float* __restrict__ h2, const float* __restrict__ W,
              const float* __restrict__ b, unsigned short* __restrict__ out, int n) {
    int wv = (int)(((long long)blockIdx.x * blockDim.x + threadIdx.x) >> 6);
    int lane = threadIdx.x & 63;
    int i0 = wv * 4;
    if (i0 >= n) return;
    float v[4], acc[4];
    #pragma unroll
    for (int r = 0; r < 4; r++) {
        int i = (i0 + r < n) ? i0 + r : n - 1;
        float t = 0.f;
        if (lane < 5)                     t = x [(size_t)i * 5 + lane];
        else if (lane >= 8 && lane < 13)  t = h1[(size_t)i * 8 + lane - 8];
        else if (lane >= 16 && lane < 21) t = h2[(size_t)i * 8 + lane - 16];
        v[r] = t;
        acc[r] = b[lane];
    }
    #pragma unroll
    for (int m = 0; m < 3; m++) {
        #pragma unroll
        for (int k = 0; k < 5; k++) {
            float wk = W[(m * 5 + k) * 64 + lane];
            #pragma unroll
            for (int r = 0; r < 4; r++) acc[r] += bcast(v[r], m * 8 + k) * wk;
        }
    }
    #pragma unroll
    for (int r = 0; r < 4; r++)
        if (i0 + r < n) out[(size_t)(i0 + r) * 64 + lane] = f2bf(fmaxf(acc[r], 0.f));
}

static inline unsigned gblk(long long n) { return (unsigned)((n + BLK - 1) / BLK); }
static inline unsigned gwv4(long long n) { return gblk(((n + 3) / 4) * 64); }
static inline unsigned gw32(long long n) { return gblk(((n + 31) / 32) * 64); }

extern "C" void kernel_launch(void* const* d_in, const int* in_sizes, int n_in,
                              void* d_out, int out_size, void* d_ws, size_t ws_size,
                              hipStream_t stream) {
    const float* game_x  = (const float*)d_in[0];
    const float* state_x = (const float*)d_in[1];
    const int*   ei_vv   = (const int*)d_in[2];
    const int*   ei_h    = (const int*)d_in[3];
    const float* ea_h    = (const float*)d_in[4];
    const int*   ei_in   = (const int*)d_in[5];
    const int*   ei_ss   = (const int*)d_in[6];
    const float* tag1_W  = (const float*)d_in[7];
    const float* tag1_b  = (const float*)d_in[8];
    const float* tag2_W  = (const float*)d_in[9];
    const float* tag2_b  = (const float*)d_in[10];
    const float* gc_Wrel = (const float*)d_in[11];
    const float* gc_b    = (const float*)d_in[12];
    const float* gc_Wroot= (const float*)d_in[13];
    const float* sage_Wl = (const float*)d_in[14];
    const float* sage_bl = (const float*)d_in[15];
    const float* sage_Wr = (const float*)d_in[16];
    const float* lin_W   = (const float*)d_in[17];
    const float* lin_b   = (const float*)d_in[18];

    const int NV  = in_sizes[0] / 5;
    const int NS  = in_sizes[1] / 6;
    const int EVV = in_sizes[2] / 2;
    const int EH  = in_sizes[3] / 2;
    const int EIN = in_sizes[5] / 2;
    const int ESS = in_sizes[6] / 2;

    const int *vv_s = ei_vv,  *vv_d = ei_vv + EVV;
    const int *h_s  = ei_h,   *h_d  = ei_h  + EH;
    const int *in_s = ei_in,  *in_d = ei_in + EIN;
    const int *ss_s = ei_ss,  *ss_d = ei_ss + ESS;

    // bin geometry
    const int ncv = (EVV + ACH - 1) / ACH;
    const int nch = (EH  + ACH - 1) / ACH;
    const int nci = (EIN + ACH - 1) / ACH;
    const int ncs = (ESS + ACH - 1) / ACH;
    const int nbv_ = (NV + 255) >> 8;
    const int nbs_ = (NS + 127) >> 7;
    const int Lv = nbv_ * ncv, Lh = nbs_ * nch, Li = nbs_ * nci, Ls = nbs_ * ncs;
    const int nB0 = (Lv + 255) / 256, nB1 = (Lh + 255) / 256,
              nB2 = (Li + 255) / 256, nB3 = (Ls + 255) / 256;

    // ---------------- workspace layout (4-byte words; ws >= 256 MiB) ---------
    float* wsf = (float*)d_ws;
    size_t o = 0;
    unsigned short* gx_bf = (unsigned short*)(wsf + o);   // NV x 64 bf16
    o += (size_t)NV * 32;
    float* B1 = wsf + o; o += (size_t)NS * 64;            // binned vv|in|ss | aggH | hA_bf
    float* B2 = wsf + o; o += (size_t)NS * 64;            // binned h | aggI(ssum) | hB_bf
    float* B4 = wsf + o; o += (size_t)NS * 32;            // H1+H2 packets (NV*16) | sx2_bf
    float* B5 = wsf + o; o += (size_t)NS * 32;            // P0 packets (NV*8) | hC_bf
    int*  vvsrc = (int*)(wsf + o); o += (size_t)EVV;
    int*  sssrc = (int*)(wsf + o); o += (size_t)ESS;
    int*  insrc = (int*)(wsf + o); o += (size_t)EIN;
    int2* hsw   = (int2*)(wsf + o); o += (size_t)EH * 2;
    int* T_all = (int*)(wsf + o); o += (size_t)(Lv + Lh + Li + Ls);
    int* bsum  = (int*)(wsf + o); o += 2048;
    int* rv = (int*)(wsf + o); o += (size_t)NV + 1;
    int* rh = (int*)(wsf + o); o += (size_t)NS + 1;
    int* ri = (int*)(wsf + o); o += (size_t)NS + 1;
    int* rs = (int*)(wsf + o); o += (size_t)NS + 1;
    float* dinv_s = wsf + o; o += (size_t)NS;

    int* Tv = T_all;
    int* Th = Tv + Lv;
    int* Ti = Th + Lh;
    int* Ts = Ti + Li;

    // phase-0 binned edge buffers alias B1/B2 (dead until stage B)
    unsigned* vvbin = (unsigned*)B1;
    unsigned* inbin = vvbin + EVV;
    unsigned* ssbin = inbin + EIN;
    int2* hbin = (int2*)B2;

    unsigned short* hA_bf  = (unsigned short*)B1;
    unsigned short* hB_bf  = (unsigned short*)B2;
    unsigned short* hC_bf  = (unsigned short*)B5;
    unsigned short* sx2_bf = (unsigned short*)B4;
    float* P0 = B5;                         // packed (x,dinv) NV*8 floats
    float* H1 = B4;                         // packed hop-1     NV*8 floats
    float* H2 = B4 + (size_t)NV * 8;        // packed hop-2     NV*8 floats

    // ================= Phase 0: atomic-free batched CSR build =================
    int nbins   = nbv_ + 3 * nbs_;
    int nBtot   = nB0 + nB1 + nB2 + nB3;
    k_binA1<<<ncv + nch + nci + ncs, 256, 0, stream>>>(vv_d, h_d, in_d, ss_d, Tv, Th, Ti, Ts,
                                         ncv, nch, nci, ncs, nbv_, nbs_,
                                         EVV, EH, EIN, ESS);
    k_sb2<<<nBtot, 256, 0, stream>>>(T_all, bsum, Lv, Lh, Li, Ls, nB0, nB1, nB2, nB3);
    k_st2<<<4, 1024, 0, stream>>>(bsum, nB0, nB1, nB2, nB3);
    k_sa2<<<nBtot, 256, 0, stream>>>(T_all, bsum, Lv, Lh, Li, Ls, nB0, nB1, nB2, nB3);
    k_binA2a<<<ncv + nci + ncs, 512, 0, stream>>>(vv_s, vv_d, in_s, in_d, ss_s, ss_d,
                                                  Tv, Ti, Ts, vvbin, inbin, ssbin,
                                                  ncv, nci, ncs, nbv_, nbs_,
                                                  EVV, EIN, ESS);
    k_binA2h<<<nch, 512, 0, stream>>>(h_s, h_d, ea_h, Th, hbin, nch, nbs_, EH);
    k_binB<<<nbins, 256, 0, stream>>>(vvbin, hbin, inbin, ssbin,
                                      Tv, Th, Ti, Ts,
                                      rv, rh, ri, rs,
                                      game_x, P0, dinv_s,
                                      vvsrc, hsw, insrc, sssrc,
                                      ncv, nch, nci, ncs, nbv_, nbs_,
                                      NV, NS, EVV, EH, EIN, ESS);

    // ================= Stage A: TAGConv1 on v-v (packet form) =================
    k_gather5p<<<gblk(NV), BLK, 0, stream>>>(P0, rv, vvsrc, H1, NV);
    k_gather5p<<<gblk(NV), BLK, 0, stream>>>(H1, rv, vvsrc, H2, NV);
    k_tag1_w<<<gwv4(NV), BLK, 0, stream>>>(game_x, H1, H2, tag1_W, tag1_b, gx_bf, NV);

    // ====== Stage B+C: fused h-graph (weighted) + in-graph (plain) gather =====
    k_gatherBC<<<gblk(2LL * NS * 64), BLK, 0, stream>>>(gx_bf, rh, hsw, ri, insrc,
                                                        B1, B2, NS);
    // fused GraphConv + SAGE dense (sx via LDS)
    k_gcsage_mf<<<gw32(NS), BLK, 0, stream>>>(B1, state_x, gc_Wrel, gc_Wroot, gc_b,
                                              B2, ri, sage_Wl, sage_Wr, sage_bl,
                                              sx2_bf, NS);

    // ================= Stage D: TAGConv2 hops (gathers only), then fused dense
    k_gather64<2, true><<<gblk((long long)NS * 64), BLK, 0, stream>>>(sx2_bf, rs, sssrc, nullptr, dinv_s, hA_bf, NS);
    k_gather64<2, true><<<gblk((long long)NS * 64), BLK, 0, stream>>>(hA_bf, rs, sssrc, nullptr, dinv_s, hB_bf, NS);
    k_gather64<2, true><<<gblk((long long)NS * 64), BLK, 0, stream>>>(hB_bf, rs, sssrc, nullptr, dinv_s, hC_bf, NS);
    k_tagmm<<<gw32(NS), BLK, 0, stream>>>(sx2_bf, hA_bf, hB_bf, hC_bf,
                                          tag2_W, tag2_b, lin_W, lin_b,
                                          (float*)d_out, NS);
}

// Round 7
// 388.791 us; speedup vs baseline: 1.0583x; 1.0583x over previous
//
#include <hip/hip_runtime.h>

#define BLK 256
#define ACH 4096   // edges per block in bin passes

// broadcast lane l of v across the wave (l wave-uniform; dynamic is legal)
__device__ __forceinline__ float bcast(float v, int l) {
    return __int_as_float(__builtin_amdgcn_readlane(__float_as_int(v), l));
}
// fp32 <-> bf16 (round-to-nearest-even)
__device__ __forceinline__ unsigned short f2bf(float f) {
    unsigned u = __float_as_uint(f);
    return (unsigned short)((u + 0x7FFFu + ((u >> 16) & 1u)) >> 16);
}
__device__ __forceinline__ float bf2f(unsigned short b) {
    return __uint_as_float(((unsigned)b) << 16);
}

// ---------------- MFMA fragment types ------
typedef __attribute__((ext_vector_type(8))) short bf16x8;
typedef __attribute__((ext_vector_type(4))) float f32x4;

// split 8 fp32 (scaled) into hi/lo bf16 fragments: v ~= hi + lo
__device__ __forceinline__ void split8s(const float* p, float s, bf16x8& h, bf16x8& l) {
    #pragma unroll
    for (int j = 0; j < 8; j++) {
        float v = p[j] * s;
        unsigned short hb = f2bf(v);
        h[j] = (short)hb;
        l[j] = (short)f2bf(v - bf2f(hb));
    }
}
// gather W[kbase+j][col] (stride-64 fp32), split hi/lo
__device__ __forceinline__ void loadWsplit(const float* W, int kbase, int col,
                                           bf16x8& h, bf16x8& l) {
    #pragma unroll
    for (int j = 0; j < 8; j++) {
        float v = W[(size_t)(kbase + j) * 64 + col];
        unsigned short hb = f2bf(v);
        h[j] = (short)hb;
        l[j] = (short)f2bf(v - bf2f(hb));
    }
}

// ================= atomic-free CSR build (two-level binned counting sort) ====

__global__ void k_binA1(const int* __restrict__ vd, const int* __restrict__ hd,
                        const int* __restrict__ id_, const int* __restrict__ sd,
                        int* __restrict__ Tv, int* __restrict__ Th,
                        int* __restrict__ Ti, int* __restrict__ Ts,
                        int ncv, int nch, int nci, int ncs,
                        int nbv_, int nbs_, int Ev, int Eh, int Ei, int Es) {
    __shared__ int cnt[512];
    int blk = blockIdx.x, t = threadIdx.x;
    const int* dd; int* T; int c, nc, nb, E, sf;
    if (blk < ncv)                 { dd = vd;  T = Tv; c = blk;               nc = ncv; nb = nbv_; E = Ev; sf = 8; }
    else if (blk < ncv + nch)      { dd = hd;  T = Th; c = blk - ncv;         nc = nch; nb = nbs_; E = Eh; sf = 7; }
    else if (blk < ncv + nch + nci){ dd = id_; T = Ti; c = blk - ncv - nch;   nc = nci; nb = nbs_; E = Ei; sf = 7; }
    else                           { dd = sd;  T = Ts; c = blk - ncv - nch - nci; nc = ncs; nb = nbs_; E = Es; sf = 7; }
    cnt[t] = 0; cnt[t + 256] = 0;
    __syncthreads();
    int p0 = c * ACH, p1 = min(E, p0 + ACH);
    for (int p = p0 + t; p < p1; p += 256) atomicAdd(&cnt[dd[p] >> sf], 1);
    __syncthreads();
    for (int b = t; b < nb; b += 256) T[(size_t)b * nc + c] = cnt[b];
}

// 3-level exclusive scan over the 4 concatenated T arrays (in place)
__global__ void k_sb2(int* __restrict__ T, int* __restrict__ bsum,
                      int L0, int L1, int L2, int L3,
                      int nB0, int nB1, int nB2, int nB3) {
    __shared__ int sh[256];
    int blk = blockIdx.x;
    int lb, off, L;
    if (blk < nB0)                  { lb = blk;                 off = 0;            L = L0; }
    else if (blk < nB0 + nB1)       { lb = blk - nB0;           off = L0;           L = L1; }
    else if (blk < nB0 + nB1 + nB2) { lb = blk - nB0 - nB1;     off = L0 + L1;      L = L2; }
    else                            { lb = blk - nB0 - nB1 - nB2; off = L0 + L1 + L2; L = L3; }
    int i = lb * 256 + threadIdx.x;
    int v = (i < L) ? T[off + i] : 0;
    sh[threadIdx.x] = v; __syncthreads();
    for (int o2 = 1; o2 < 256; o2 <<= 1) {
        int tmp = (threadIdx.x >= o2) ? sh[threadIdx.x - o2] : 0;
        __syncthreads();
        sh[threadIdx.x] += tmp; __syncthreads();
    }
    if (i < L) T[off + i] = sh[threadIdx.x] - v;
    if (threadIdx.x == 255) bsum[blk] = sh[255];
}

__global__ void k_st2(int* __restrict__ bsum, int nB0, int nB1, int nB2, int nB3) {
    __shared__ int sh[1024];
    int g = blockIdx.x;
    int off = (g == 0) ? 0 : (g == 1) ? nB0 : (g == 2) ? nB0 + nB1 : nB0 + nB1 + nB2;
    int nb  = (g == 0) ? nB0 : (g == 1) ? nB1 : (g == 2) ? nB2 : nB3;
    int tid = threadIdx.x;
    int v = (tid < nb) ? bsum[off + tid] : 0;
    sh[tid] = v; __syncthreads();
    for (int o2 = 1; o2 < 1024; o2 <<= 1) {
        int t = (tid >= o2) ? sh[tid - o2] : 0;
        __syncthreads();
        sh[tid] += t; __syncthreads();
    }
    if (tid < nb) bsum[off + tid] = sh[tid] - v;
}

__global__ void k_sa2(int* __restrict__ T, const int* __restrict__ bsum,
                      int L0, int L1, int L2, int L3,
                      int nB0, int nB1, int nB2, int nB3) {
    int blk = blockIdx.x;
    int lb, off, L;
    if (blk < nB0)                  { lb = blk;                 off = 0;            L = L0; }
    else if (blk < nB0 + nB1)       { lb = blk - nB0;           off = L0;           L = L1; }
    else if (blk < nB0 + nB1 + nB2) { lb = blk - nB0 - nB1;     off = L0 + L1;      L = L2; }
    else                            { lb = blk - nB0 - nB1 - nB2; off = L0 + L1 + L2; L = L3; }
    int i = lb * 256 + threadIdx.x;
    if (i < L) T[off + i] += bsum[blk];
}

// A2 (no-weight graphs vv/in/ss): register-stage 8 edges/thread, LDS counting
// sort by bin, stream out -> piecewise-contiguous global writes.
__global__ __launch_bounds__(512)
void k_binA2a(const int* __restrict__ vs, const int* __restrict__ vd,
              const int* __restrict__ is_, const int* __restrict__ id_,
              const int* __restrict__ ss_, const int* __restrict__ sd,
              const int* __restrict__ Tv, const int* __restrict__ Ti,
              const int* __restrict__ Ts,
              unsigned* __restrict__ vvbin, unsigned* __restrict__ inbin,
              unsigned* __restrict__ ssbin,
              int ncv, int nci, int ncs, int nbv_, int nbs_,
              int Ev, int Ei, int Es) {
    __shared__ int gbase[512], lscan[512], lcur[512];
    __shared__ unsigned sval[ACH];
    __shared__ int sdst[ACH];
    int blk = blockIdx.x, t = threadIdx.x;
    const int *srcp, *dstp, *T; unsigned* bin; int c, nc, nb, E, sf;
    if (blk < ncv)            { srcp = vs;  dstp = vd;  T = Tv; bin = vvbin; c = blk;             nc = ncv; nb = nbv_; E = Ev; sf = 8; }
    else if (blk < ncv + nci) { srcp = is_; dstp = id_; T = Ti; bin = inbin; c = blk - ncv;       nc = nci; nb = nbs_; E = Ei; sf = 7; }
    else                      { srcp = ss_; dstp = sd;  T = Ts; bin = ssbin; c = blk - ncv - nci; nc = ncs; nb = nbs_; E = Es; sf = 7; }
    int msk = (1 << sf) - 1;
    int p0 = c * ACH, p1 = min(E, p0 + ACH);
    if (t < nb) gbase[t] = T[(size_t)t * nc + c];
    lcur[t] = 0;
    int myS[8], myD[8];
    #pragma unroll
    for (int i = 0; i < 8; i++) {
        int p = p0 + t + i * 512;
        if (p < p1) { myS[i] = srcp[p]; myD[i] = dstp[p]; }
        else myD[i] = -1;
    }
    __syncthreads();
    #pragma unroll
    for (int i = 0; i < 8; i++)
        if (myD[i] >= 0) atomicAdd(&lcur[myD[i] >> sf], 1);
    __syncthreads();
    int v = lcur[t];
    lscan[t] = v;
    __syncthreads();
    for (int off = 1; off < 512; off <<= 1) {
        int tmp = (t >= off) ? lscan[t - off] : 0;
        __syncthreads();
        lscan[t] += tmp;
        __syncthreads();
    }
    int excl = lscan[t] - v;
    __syncthreads();
    lscan[t] = excl;
    lcur[t] = 0;
    __syncthreads();
    #pragma unroll
    for (int i = 0; i < 8; i++) {
        if (myD[i] < 0) continue;
        int b = myD[i] >> sf;
        int r = atomicAdd(&lcur[b], 1);
        int pos = lscan[b] + r;
        sval[pos] = ((unsigned)myS[i] << sf) | (unsigned)(myD[i] & msk);
        sdst[pos] = gbase[b] + r;
    }
    __syncthreads();
    int cntE = p1 - p0;
    for (int q = t; q < cntE; q += 512) bin[sdst[q]] = sval[q];
}

// A2 for the weighted h graph (int2 payload)
__global__ __launch_bounds__(512)
void k_binA2h(const int* __restrict__ hs, const int* __restrict__ hd,
              const float* __restrict__ hw, const int* __restrict__ Th,
              int2* __restrict__ hbin, int nch, int nbs_, int Eh) {
    __shared__ int gbase[512], lscan[512], lcur[512];
    __shared__ unsigned sval[ACH];
    __shared__ int sdst[ACH];
    __shared__ float swt[ACH];
    int c = blockIdx.x, t = threadIdx.x;
    const int sf = 7, msk = 127;
    int p0 = c * ACH, p1 = min(Eh, p0 + ACH);
    if (t < nbs_) gbase[t] = Th[(size_t)t * nch + c];
    lcur[t] = 0;
    int myS[8], myD[8]; float myW[8];
    #pragma unroll
    for (int i = 0; i < 8; i++) {
        int p = p0 + t + i * 512;
        if (p < p1) { myS[i] = hs[p]; myD[i] = hd[p]; myW[i] = hw[p]; }
        else myD[i] = -1;
    }
    __syncthreads();
    #pragma unroll
    for (int i = 0; i < 8; i++)
        if (myD[i] >= 0) atomicAdd(&lcur[myD[i] >> sf], 1);
    __syncthreads();
    int v = lcur[t];
    lscan[t] = v;
    __syncthreads();
    for (int off = 1; off < 512; off <<= 1) {
        int tmp = (t >= off) ? lscan[t - off] : 0;
        __syncthreads();
        lscan[t] += tmp;
        __syncthreads();
    }
    int excl = lscan[t] - v;
    __syncthreads();
    lscan[t] = excl;
    lcur[t] = 0;
    __syncthreads();
    #pragma unroll
    for (int i = 0; i < 8; i++) {
        if (myD[i] < 0) continue;
        int b = myD[i] >> sf;
        int r = atomicAdd(&lcur[b], 1);
        int pos = lscan[b] + r;
        sval[pos] = ((unsigned)myS[i] << sf) | (unsigned)(myD[i] & msk);
        sdst[pos] = gbase[b] + r;
        swt[pos] = myW[i];
    }
    __syncthreads();
    int cntE = p1 - p0;
    for (int q = t; q < cntE; q += 512)
        hbin[sdst[q]] = make_int2((int)sval[q], __float_as_int(swt[q]));
}

// binB: per-bin dst-local hist -> rowptr + dinv + final CSR scatter.
// For the vv graph (g==0) it also emits the packed (x[5], rsqrt(deg)) node
// packet used by the gather5p hops.
__global__ void k_binB(const unsigned* __restrict__ vvbin, const int2* __restrict__ hbin,
                       const unsigned* __restrict__ inbin, const unsigned* __restrict__ ssbin,
                       const int* __restrict__ Tv, const int* __restrict__ Th,
                       const int* __restrict__ Ti, const int* __restrict__ Ts,
                       int* __restrict__ rv, int* __restrict__ rh,
                       int* __restrict__ ri, int* __restrict__ rs,
                       const float* __restrict__ gx5, float* __restrict__ P0,
                       float* __restrict__ dinv_s,
                       int* __restrict__ vvsrc, int2* __restrict__ hsw,
                       int* __restrict__ insrc, int* __restrict__ sssrc,
                       int ncv, int nch, int nci, int ncs,
                       int nbv_, int nbs_, int nv, int ns,
                       int Ev, int Eh, int Ei, int Es) {
    __shared__ int cnt[256]; __shared__ int pre[256]; __shared__ int cur[256];
    int blk = blockIdx.x, t = threadIdx.x;
    int g, b, nb, nc, sf, n, E; const int* T; int* rp;
    if (blk < nbv_)                 { g = 0; b = blk;                 nb = nbv_; nc = ncv; sf = 8; n = nv; E = Ev; T = Tv; rp = rv; }
    else if (blk < nbv_ + nbs_)     { g = 1; b = blk - nbv_;          nb = nbs_; nc = nch; sf = 7; n = ns; E = Eh; T = Th; rp = rh; }
    else if (blk < nbv_ + 2 * nbs_) { g = 2; b = blk - nbv_ - nbs_;   nb = nbs_; nc = nci; sf = 7; n = ns; E = Ei; T = Ti; rp = ri; }
    else                            { g = 3; b = blk - nbv_ - 2 * nbs_; nb = nbs_; nc = ncs; sf = 7; n = ns; E = Es; T = Ts; rp = rs; }
    int W = 1 << sf, msk = W - 1;
    int e0 = T[(size_t)b * nc];
    int e1 = (b + 1 < nb) ? T[(size_t)(b + 1) * nc] : E;
    cnt[t] = 0; __syncthreads();
    for (int p = e0 + t; p < e1; p += 256) {
        unsigned pk = (g == 1) ? (unsigned)hbin[p].x
                    : (g == 0) ? vvbin[p] : (g == 2) ? inbin[p] : ssbin[p];
        atomicAdd(&cnt[pk & msk], 1);
    }
    __syncthreads();
    int v = cnt[t];
    pre[t] = v; __syncthreads();
    for (int o2 = 1; o2 < 256; o2 <<= 1) {
        int tmp = (t >= o2) ? pre[t - o2] : 0;
        __syncthreads();
        pre[t] += tmp; __syncthreads();
    }
    int excl = pre[t] - v;
    int d = b * W + t;
    if (t < W && d < n) {
        rp[d] = e0 + excl;
        if (g == 0) {
            const float* xp = gx5 + (size_t)d * 5;
            float di = v > 0 ? rsqrtf((float)v) : 0.f;
            ((float4*)P0)[(size_t)d * 2]     = make_float4(xp[0], xp[1], xp[2], xp[3]);
            ((float4*)P0)[(size_t)d * 2 + 1] = make_float4(xp[4], di, 0.f, 0.f);
        } else if (g == 3) {
            dinv_s[d] = v > 0 ? rsqrtf((float)v) : 0.f;
        }
    }
    cur[t] = e0 + excl;
    __syncthreads();
    for (int p = e0 + t; p < e1; p += 256) {
        if (g == 1) {
            int2 r = hbin[p];
            unsigned pk = (unsigned)r.x;
            int pos = atomicAdd(&cur[pk & msk], 1);
            hsw[pos] = make_int2((int)(pk >> sf), r.y);
        } else {
            unsigned pk = (g == 0) ? vvbin[p] : (g == 2) ? inbin[p] : ssbin[p];
            int pos = atomicAdd(&cur[pk & msk], 1);
            int sv = (int)(pk >> sf);
            if (g == 0)      vvsrc[pos] = sv;
            else if (g == 2) insrc[pos] = sv;
            else             sssrc[pos] = sv;
        }
    }
    if (b == 0 && t == 0) rp[n] = E;
}

// ================= gathers =================

// gather over 32B (x[5],dinv) packets; output is also a packet for the next hop
__global__ void k_gather5p(const float* __restrict__ Pin, const int* __restrict__ rowptr,
                           const int* __restrict__ csr_src, float* __restrict__ Pout, int n) {
    int d = blockIdx.x * blockDim.x + threadIdx.x;
    if (d >= n) return;
    int b = rowptr[d], e = rowptr[d + 1];
    float dd = Pin[(size_t)d * 8 + 5];
    float a0 = 0, a1 = 0, a2 = 0, a3 = 0, a4 = 0;
    int p = b;
    for (; p + 4 <= e; p += 4) {
        int s0 = csr_src[p], s1 = csr_src[p+1], s2 = csr_src[p+2], s3 = csr_src[p+3];
        float4 x0a = ((const float4*)Pin)[(size_t)s0 * 2], x0b = ((const float4*)Pin)[(size_t)s0 * 2 + 1];
        float4 x1a = ((const float4*)Pin)[(size_t)s1 * 2], x1b = ((const float4*)Pin)[(size_t)s1 * 2 + 1];
        float4 x2a = ((const float4*)Pin)[(size_t)s2 * 2], x2b = ((const float4*)Pin)[(size_t)s2 * 2 + 1];
        float4 x3a = ((const float4*)Pin)[(size_t)s3 * 2], x3b = ((const float4*)Pin)[(size_t)s3 * 2 + 1];
        float w0 = dd * x0b.y, w1 = dd * x1b.y, w2 = dd * x2b.y, w3 = dd * x3b.y;
        a0 += x0a.x*w0 + x1a.x*w1 + x2a.x*w2 + x3a.x*w3;
        a1 += x0a.y*w0 + x1a.y*w1 + x2a.y*w2 + x3a.y*w3;
        a2 += x0a.z*w0 + x1a.z*w1 + x2a.z*w2 + x3a.z*w3;
        a3 += x0a.w*w0 + x1a.w*w1 + x2a.w*w2 + x3a.w*w3;
        a4 += x0b.x*w0 + x1b.x*w1 + x2b.x*w2 + x3b.x*w3;
    }
    for (; p < e; p++) {
        int s = csr_src[p];
        float4 xa = ((const float4*)Pin)[(size_t)s * 2], xb = ((const float4*)Pin)[(size_t)s * 2 + 1];
        float w = dd * xb.y;
        a0 += xa.x*w; a1 += xa.y*w; a2 += xa.z*w; a3 += xa.w*w; a4 += xb.x*w;
    }
    ((float4*)Pout)[(size_t)d * 2]     = make_float4(a0, a1, a2, a3);
    ((float4*)Pout)[(size_t)d * 2 + 1] = make_float4(a4, dd, 0.f, 0.f);
}

// Fused stage-B + stage-C gather: wave wid<n does the weighted h-graph row,
// wave wid>=n does the plain in-graph row. Both read gx_bf (shared hot set).
__global__ void k_gatherBC(const unsigned short* __restrict__ xbf,
                           const int* __restrict__ rh, const int2* __restrict__ hsw,
                           const int* __restrict__ ri, const int* __restrict__ insrc,
                           float* __restrict__ aggH, float* __restrict__ aggI, int n) {
    int wid = (int)(((long long)blockIdx.x * blockDim.x + threadIdx.x) >> 6);
    if (wid >= 2 * n) return;
    int lane = threadIdx.x & 63;
    int g = lane >> 4, q = lane & 15;
    float4 acc = make_float4(0.f, 0.f, 0.f, 0.f);
    float* outp;
    int row;
    if (wid < n) {
        row = wid;
        int b = rh[row], e = rh[row + 1];
        int p = b + g;
        for (; p + 12 < e; p += 16) {
            int2 e0 = hsw[p], e1 = hsw[p+4], e2 = hsw[p+8], e3 = hsw[p+12];
            float w0 = __int_as_float(e0.y), w1 = __int_as_float(e1.y);
            float w2 = __int_as_float(e2.y), w3 = __int_as_float(e3.y);
            ushort4 u0 = ((const ushort4*)(xbf + (size_t)e0.x * 64))[q];
            ushort4 u1 = ((const ushort4*)(xbf + (size_t)e1.x * 64))[q];
            ushort4 u2 = ((const ushort4*)(xbf + (size_t)e2.x * 64))[q];
            ushort4 u3 = ((const ushort4*)(xbf + (size_t)e3.x * 64))[q];
            acc.x += bf2f(u0.x)*w0 + bf2f(u1.x)*w1 + bf2f(u2.x)*w2 + bf2f(u3.x)*w3;
            acc.y += bf2f(u0.y)*w0 + bf2f(u1.y)*w1 + bf2f(u2.y)*w2 + bf2f(u3.y)*w3;
            acc.z += bf2f(u0.z)*w0 + bf2f(u1.z)*w1 + bf2f(u2.z)*w2 + bf2f(u3.z)*w3;
            acc.w += bf2f(u0.w)*w0 + bf2f(u1.w)*w1 + bf2f(u2.w)*w2 + bf2f(u3.w)*w3;
        }
        for (; p < e; p += 4) {
            int2 e0 = hsw[p];
            float w = __int_as_float(e0.y);
            ushort4 u = ((const ushort4*)(xbf + (size_t)e0.x * 64))[q];
            acc.x += bf2f(u.x)*w; acc.y += bf2f(u.y)*w;
            acc.z += bf2f(u.z)*w; acc.w += bf2f(u.w)*w;
        }
        outp = aggH;
    } else {
        row = wid - n;
        int b = ri[row], e = ri[row + 1];
        int p = b + g;
        for (; p + 12 < e; p += 16) {
            int s0 = insrc[p], s1 = insrc[p+4], s2 = insrc[p+8], s3 = insrc[p+12];
            ushort4 u0 = ((const ushort4*)(xbf + (size_t)s0 * 64))[q];
            ushort4 u1 = ((const ushort4*)(xbf + (size_t)s1 * 64))[q];
            ushort4 u2 = ((const ushort4*)(xbf + (size_t)s2 * 64))[q];
            ushort4 u3 = ((const ushort4*)(xbf + (size_t)s3 * 64))[q];
            acc.x += bf2f(u0.x) + bf2f(u1.x) + bf2f(u2.x) + bf2f(u3.x);
            acc.y += bf2f(u0.y) + bf2f(u1.y) + bf2f(u2.y) + bf2f(u3.y);
            acc.z += bf2f(u0.z) + bf2f(u1.z) + bf2f(u2.z) + bf2f(u3.z);
            acc.w += bf2f(u0.w) + bf2f(u1.w) + bf2f(u2.w) + bf2f(u3.w);
        }
        for (; p < e; p += 4) {
            int s = insrc[p];
            ushort4 u = ((const ushort4*)(xbf + (size_t)s * 64))[q];
            acc.x += bf2f(u.x); acc.y += bf2f(u.y);
            acc.z += bf2f(u.z); acc.w += bf2f(u.w);
        }
        outp = aggI;
    }
    #pragma unroll
    for (int off = 16; off < 64; off <<= 1) {
        acc.x += __shfl_xor(acc.x, off, 64);
        acc.y += __shfl_xor(acc.y, off, 64);
        acc.z += __shfl_xor(acc.z, off, 64);
        acc.w += __shfl_xor(acc.w, off, 64);
    }
    if (g == 0) ((float4*)outp)[(size_t)row * 16 + q] = acc;
}

// 64-ch gather, MODE 2 (symmetric gcn norm), bf16 out — ss-graph hops
template<int MODE, bool OUTBF>
__global__ void k_gather64(const unsigned short* __restrict__ xbf, const int* __restrict__ rowptr,
                           const int* __restrict__ csr_src, const int2* __restrict__ csr_sw,
                           const float* __restrict__ dinv, void* __restrict__ outp, int n) {
    int wid = (int)(((long long)blockIdx.x * blockDim.x + threadIdx.x) >> 6);
    if (wid >= n) return;
    int lane = threadIdx.x & 63;
    int g = lane >> 4, q = lane & 15;
    int b = rowptr[wid], e = rowptr[wid + 1];
    float dd = (MODE == 2) ? dinv[wid] : 0.f;
    float4 acc = make_float4(0.f, 0.f, 0.f, 0.f);
    int p = b + g;
    for (; p + 12 < e; p += 16) {
        int s0, s1, s2, s3;
        float w0 = 1.f, w1 = 1.f, w2 = 1.f, w3 = 1.f;
        if (MODE == 1) {
            int2 e0 = csr_sw[p], e1 = csr_sw[p+4], e2 = csr_sw[p+8], e3 = csr_sw[p+12];
            s0 = e0.x; w0 = __int_as_float(e0.y);
            s1 = e1.x; w1 = __int_as_float(e1.y);
            s2 = e2.x; w2 = __int_as_float(e2.y);
            s3 = e3.x; w3 = __int_as_float(e3.y);
        } else {
            s0 = csr_src[p]; s1 = csr_src[p+4]; s2 = csr_src[p+8]; s3 = csr_src[p+12];
            if (MODE == 2) {
                w0 = dd * dinv[s0]; w1 = dd * dinv[s1];
                w2 = dd * dinv[s2]; w3 = dd * dinv[s3];
            }
        }
        ushort4 u0 = ((const ushort4*)(xbf + (size_t)s0 * 64))[q];
        ushort4 u1 = ((const ushort4*)(xbf + (size_t)s1 * 64))[q];
        ushort4 u2 = ((const ushort4*)(xbf + (size_t)s2 * 64))[q];
        ushort4 u3 = ((const ushort4*)(xbf + (size_t)s3 * 64))[q];
        acc.x += bf2f(u0.x)*w0 + bf2f(u1.x)*w1 + bf2f(u2.x)*w2 + bf2f(u3.x)*w3;
        acc.y += bf2f(u0.y)*w0 + bf2f(u1.y)*w1 + bf2f(u2.y)*w2 + bf2f(u3.y)*w3;
        acc.z += bf2f(u0.z)*w0 + bf2f(u1.z)*w1 + bf2f(u2.z)*w2 + bf2f(u3.z)*w3;
        acc.w += bf2f(u0.w)*w0 + bf2f(u1.w)*w1 + bf2f(u2.w)*w2 + bf2f(u3.w)*w3;
    }
    for (; p < e; p += 4) {
        int s; float w = 1.f;
        if (MODE == 1) { int2 e0 = csr_sw[p]; s = e0.x; w = __int_as_float(e0.y); }
        else { s = csr_src[p]; if (MODE == 2) w = dd * dinv[s]; }
        ushort4 u = ((const ushort4*)(xbf + (size_t)s * 64))[q];
        acc.x += bf2f(u.x)*w; acc.y += bf2f(u.y)*w;
        acc.z += bf2f(u.z)*w; acc.w += bf2f(u.w)*w;
    }
    #pragma unroll
    for (int off = 16; off < 64; off <<= 1) {
        acc.x += __shfl_xor(acc.x, off, 64);
        acc.y += __shfl_xor(acc.y, off, 64);
        acc.z += __shfl_xor(acc.z, off, 64);
        acc.w += __shfl_xor(acc.w, off, 64);
    }
    if (g == 0) {
        if (OUTBF) {
            ushort4 ov;
            ov.x = f2bf(acc.x); ov.y = f2bf(acc.y); ov.z = f2bf(acc.z); ov.w = f2bf(acc.w);
            ((ushort4*)outp)[(size_t)wid * 16 + q] = ov;
        } else {
            ((float4*)outp)[(size_t)wid * 16 + q] = acc;
        }
    }
}

// ============ dense combines (MFMA wave GEMMs, 32 rows x 64 cols/wave) =======
// k-map: A and B both loaded with k = kh*32 + g*8 + j (g = lane>>4, j = elem).
// C/D layout (HW-verified): col = lane&15, row = g*4 + reg.
// NOTE (round 6 lesson): routing sx through LDS [32][64] fp32 = 16-way bank
// conflict on re-read (256B row stride) -> 450K conflicts, 61us. Keep gc and
// sage as separate kernels; the fp32 sx buffer is L2-resident (~2us traffic).

// sx = relu(b + agg@Wrel + state@Wroot)   (fp32 out; only read by sage)
__global__ __launch_bounds__(256)
void k_gc_mf(const float* __restrict__ agg, const float* __restrict__ st,
             const float* __restrict__ Wrel, const float* __restrict__ Wroot,
             const float* __restrict__ b, float* __restrict__ out, int n) {
    int wv = (int)(((long long)blockIdx.x * blockDim.x + threadIdx.x) >> 6);
    int lane = threadIdx.x & 63;
    int r0 = wv * 32;
    if (r0 >= n) return;
    int lm = lane & 15, g = lane >> 4;
    bf16x8 axh[2][2], axl[2][2], arh[2], arl[2];
    #pragma unroll
    for (int mt = 0; mt < 2; mt++) {
        int row = r0 + mt * 16 + lm; if (row >= n) row = n - 1;
        #pragma unroll
        for (int kh = 0; kh < 2; kh++)
            split8s(agg + (size_t)row * 64 + kh * 32 + g * 8, 1.f, axh[mt][kh], axl[mt][kh]);
        #pragma unroll
        for (int j = 0; j < 8; j++) {
            int k = g * 8 + j;
            float v = (k < 6) ? st[(size_t)row * 6 + k] : 0.f;
            unsigned short hb = f2bf(v);
            arh[mt][j] = (short)hb;
            arl[mt][j] = (short)f2bf(v - bf2f(hb));
        }
    }
    #pragma unroll
    for (int nt = 0; nt < 4; nt++) {
        int col = nt * 16 + lm;
        bf16x8 bh[2], blo[2], brh, brl;
        #pragma unroll
        for (int kh = 0; kh < 2; kh++) loadWsplit(Wrel, kh * 32 + g * 8, col, bh[kh], blo[kh]);
        #pragma unroll
        for (int j = 0; j < 8; j++) {
            int k = g * 8 + j;
            float v = (k < 6) ? Wroot[(size_t)k * 64 + col] : 0.f;
            unsigned short hb = f2bf(v);
            brh[j] = (short)hb;
            brl[j] = (short)f2bf(v - bf2f(hb));
        }
        #pragma unroll
        for (int mt = 0; mt < 2; mt++) {
            f32x4 acc = {0.f, 0.f, 0.f, 0.f};
            #pragma unroll
            for (int kh = 0; kh < 2; kh++) {
                acc = __builtin_amdgcn_mfma_f32_16x16x32_bf16(axh[mt][kh], bh[kh],  acc, 0, 0, 0);
                acc = __builtin_amdgcn_mfma_f32_16x16x32_bf16(axl[mt][kh], bh[kh],  acc, 0, 0, 0);
                acc = __builtin_amdgcn_mfma_f32_16x16x32_bf16(axh[mt][kh], blo[kh], acc, 0, 0, 0);
            }
            acc = __builtin_amdgcn_mfma_f32_16x16x32_bf16(arh[mt], brh, acc, 0, 0, 0);
            acc = __builtin_amdgcn_mfma_f32_16x16x32_bf16(arl[mt], brh, acc, 0, 0, 0);
            acc = __builtin_amdgcn_mfma_f32_16x16x32_bf16(arh[mt], brl, acc, 0, 0, 0);
            #pragma unroll
            for (int r = 0; r < 4; r++) {
                int row = r0 + mt * 16 + g * 4 + r;
                if (row < n)
                    out[(size_t)row * 64 + col] = fmaxf(b[col] + acc[r], 0.f);
            }
        }
    }
}

// sx2_bf = bf16(relu(bl + (ssum/max(cnt,1))@Wl + sx@Wr))
__global__ __launch_bounds__(256)
void k_sage_mf(const float* __restrict__ ssum, const int* __restrict__ rp,
               const float* __restrict__ sx, const float* __restrict__ Wl,
               const float* __restrict__ Wr, const float* __restrict__ bl,
               unsigned short* __restrict__ out, int n) {
    int wv = (int)(((long long)blockIdx.x * blockDim.x + threadIdx.x) >> 6);
    int lane = threadIdx.x & 63;
    int r0 = wv * 32;
    if (r0 >= n) return;
    int lm = lane & 15, g = lane >> 4;
    bf16x8 axh[2][2], axl[2][2], ayh[2][2], ayl[2][2];
    #pragma unroll
    for (int mt = 0; mt < 2; mt++) {
        int row = r0 + mt * 16 + lm; if (row >= n) row = n - 1;
        float cnt = (float)(rp[row + 1] - rp[row]);
        float rs = 1.f / fmaxf(cnt, 1.f);
        #pragma unroll
        for (int kh = 0; kh < 2; kh++) {
            split8s(ssum + (size_t)row * 64 + kh * 32 + g * 8, rs,  axh[mt][kh], axl[mt][kh]);
            split8s(sx   + (size_t)row * 64 + kh * 32 + g * 8, 1.f, ayh[mt][kh], ayl[mt][kh]);
        }
    }
    #pragma unroll
    for (int nt = 0; nt < 4; nt++) {
        int col = nt * 16 + lm;
        bf16x8 blh[2], bll[2], brh[2], brl[2];
        #pragma unroll
        for (int kh = 0; kh < 2; kh++) {
            loadWsplit(Wl, kh * 32 + g * 8, col, blh[kh], bll[kh]);
            loadWsplit(Wr, kh * 32 + g * 8, col, brh[kh], brl[kh]);
        }
        #pragma unroll
        for (int mt = 0; mt < 2; mt++) {
            f32x4 acc = {0.f, 0.f, 0.f, 0.f};
            #pragma unroll
            for (int kh = 0; kh < 2; kh++) {
                acc = __builtin_amdgcn_mfma_f32_16x16x32_bf16(axh[mt][kh], blh[kh], acc, 0, 0, 0);
                acc = __builtin_amdgcn_mfma_f32_16x16x32_bf16(axl[mt][kh], blh[kh], acc, 0, 0, 0);
                acc = __builtin_amdgcn_mfma_f32_16x16x32_bf16(axh[mt][kh], bll[kh], acc, 0, 0, 0);
                acc = __builtin_amdgcn_mfma_f32_16x16x32_bf16(ayh[mt][kh], brh[kh], acc, 0, 0, 0);
                acc = __builtin_amdgcn_mfma_f32_16x16x32_bf16(ayl[mt][kh], brh[kh], acc, 0, 0, 0);
                acc = __builtin_amdgcn_mfma_f32_16x16x32_bf16(ayh[mt][kh], brl[kh], acc, 0, 0, 0);
            }
            #pragma unroll
            for (int r = 0; r < 4; r++) {
                int row = r0 + mt * 16 + g * 4 + r;
                if (row < n)
                    out[(size_t)row * 64 + col] = f2bf(fmaxf(bl[col] + acc[r], 0.f));
            }
        }
    }
}

// Fused TAG2 combine + final linear:
// out8 = lin_b + relu(tag2_b + x0@W0 + x1@W1 + x2@W2 + x3@W3) @ lin_W
__global__ __launch_bounds__(256)
void k_tagmm(const unsigned short* __restrict__ x0, const unsigned short* __restrict__ x1,
             const unsigned short* __restrict__ x2, const unsigned short* __restrict__ x3,
             const float* __restrict__ W4, const float* __restrict__ tb,
             const float* __restrict__ lW, const float* __restrict__ lb,
             float* __restrict__ out, int n) {
    __shared__ float lds[4][32][64];
    int tid = threadIdx.x;
    int wv = (int)(((long long)blockIdx.x * blockDim.x + tid) >> 6);
    int w = (tid >> 6) & 3;
    int lane = tid & 63;
    int lm = lane & 15, g = lane >> 4;
    int r0 = wv * 32;
    bool active = (r0 < n);
    int r0c = active ? r0 : 0;
    const unsigned short* xs[4] = {x0, x1, x2, x3};
    f32x4 acc[2][4];
    #pragma unroll
    for (int mt = 0; mt < 2; mt++)
        #pragma unroll
        for (int nt = 0; nt < 4; nt++) acc[mt][nt] = (f32x4){0.f, 0.f, 0.f, 0.f};
    #pragma unroll
    for (int inp = 0; inp < 4; inp++) {
        const unsigned short* xp = xs[inp];
        const float* W = W4 + inp * 4096;
        bf16x8 a[2][2];
        #pragma unroll
        for (int mt = 0; mt < 2; mt++) {
            int row = r0c + mt * 16 + lm; if (row >= n) row = n - 1;
            #pragma unroll
            for (int kh = 0; kh < 2; kh++)
                a[mt][kh] = *(const bf16x8*)(xp + (size_t)row * 64 + kh * 32 + g * 8);
        }
        #pragma unroll
        for (int nt = 0; nt < 4; nt++) {
            int col = nt * 16 + lm;
            bf16x8 bh[2], blo[2];
            #pragma unroll
            for (int kh = 0; kh < 2; kh++) loadWsplit(W, kh * 32 + g * 8, col, bh[kh], blo[kh]);
            #pragma unroll
            for (int mt = 0; mt < 2; mt++) {
                #pragma unroll
                for (int kh = 0; kh < 2; kh++) {
                    acc[mt][nt] = __builtin_amdgcn_mfma_f32_16x16x32_bf16(a[mt][kh], bh[kh],  acc[mt][nt], 0, 0, 0);
                    acc[mt][nt] = __builtin_amdgcn_mfma_f32_16x16x32_bf16(a[mt][kh], blo[kh], acc[mt][nt], 0, 0, 0);
                }
            }
        }
    }
    #pragma unroll
    for (int mt = 0; mt < 2; mt++)
        #pragma unroll
        for (int nt = 0; nt < 4; nt++) {
            int col = nt * 16 + lm;
            float bias = tb[col];
            #pragma unroll
            for (int r = 0; r < 4; r++)
                lds[w][mt * 16 + g * 4 + r][col] = fmaxf(bias + acc[mt][nt][r], 0.f);
        }
    __syncthreads();
    bf16x8 bh2[2], bl2[2];
    #pragma unroll
    for (int kh = 0; kh < 2; kh++) {
        #pragma unroll
        for (int j = 0; j < 8; j++) {
            int k = kh * 32 + g * 8 + j;
            float v = (lm < 8) ? lW[k * 8 + lm] : 0.f;
            unsigned short hb = f2bf(v);
            bh2[kh][j] = (short)hb;
            bl2[kh][j] = (short)f2bf(v - bf2f(hb));
        }
    }
    #pragma unroll
    for (int mt = 0; mt < 2; mt++) {
        bf16x8 ah[2], al[2];
        #pragma unroll
        for (int kh = 0; kh < 2; kh++) {
            #pragma unroll
            for (int j = 0; j < 8; j++) {
                float v = lds[w][mt * 16 + lm][kh * 32 + g * 8 + j];
                unsigned short hb = f2bf(v);
                ah[kh][j] = (short)hb;
                al[kh][j] = (short)f2bf(v - bf2f(hb));
            }
        }
        f32x4 oacc = {0.f, 0.f, 0.f, 0.f};
        #pragma unroll
        for (int kh = 0; kh < 2; kh++) {
            oacc = __builtin_amdgcn_mfma_f32_16x16x32_bf16(ah[kh], bh2[kh], oacc, 0, 0, 0);
            oacc = __builtin_amdgcn_mfma_f32_16x16x32_bf16(al[kh], bh2[kh], oacc, 0, 0, 0);
            oacc = __builtin_amdgcn_mfma_f32_16x16x32_bf16(ah[kh], bl2[kh], oacc, 0, 0, 0);
        }
        if (lm < 8) {
            #pragma unroll
            for (int r = 0; r < 4; r++) {
                int row = r0 + mt * 16 + g * 4 + r;
                if (active && row < n) out[(size_t)row * 8 + lm] = oacc[r] + lb[lm];
            }
        }
    }
}

// gx_bf = bf16(relu(b + x@W0 + h1@W1 + h2@W2))  (K=5 inputs; VALU is fine)
// h1/h2 are 8-float packets (stride 8)
__global__ __launch_bounds__(256, 4)
void k_tag1_w(const float* __restrict__ x, const float* __restrict__ h1,
              const float* __restrict__ h2, const float* __restrict__ W,
              const float* __restrict__ b, unsigned short* __restrict__ out, int n) {
    int wv = (int)(((long long)blockIdx.x * blockDim.x + threadIdx.x) >> 6);
    int lane = threadIdx.x & 63;
    int i0 = wv * 4;
    if (i0 >= n) return;
    float v[4], acc[4];
    #pragma unroll
    for (int r = 0; r < 4; r++) {
        int i = (i0 + r < n) ? i0 + r : n - 1;
        float t = 0.f;
        if (lane < 5)                     t = x [(size_t)i * 5 + lane];
        else if (lane >= 8 && lane < 13)  t = h1[(size_t)i * 8 + lane - 8];
        else if (lane >= 16 && lane < 21) t = h2[(size_t)i * 8 + lane - 16];
        v[r] = t;
        acc[r] = b[lane];
    }
    #pragma unroll
    for (int m = 0; m < 3; m++) {
        #pragma unroll
        for (int k = 0; k < 5; k++) {
            float wk = W[(m * 5 + k) * 64 + lane];
            #pragma unroll
            for (int r = 0; r < 4; r++) acc[r] += bcast(v[r], m * 8 + k) * wk;
        }
    }
    #pragma unroll
    for (int r = 0; r < 4; r++)
        if (i0 + r < n) out[(size_t)(i0 + r) * 64 + lane] = f2bf(fmaxf(acc[r], 0.f));
}

static inline unsigned gblk(long long n) { return (unsigned)((n + BLK - 1) / BLK); }
static inline unsigned gwv4(long long n) { return gblk(((n + 3) / 4) * 64); }
static inline unsigned gw32(long long n) { return gblk(((n + 31) / 32) * 64); }

extern "C" void kernel_launch(void* const* d_in, const int* in_sizes, int n_in,
                              void* d_out, int out_size, void* d_ws, size_t ws_size,
                              hipStream_t stream) {
    const float* game_x  = (const float*)d_in[0];
    const float* state_x = (const float*)d_in[1];
    const int*   ei_vv   = (const int*)d_in[2];
    const int*   ei_h    = (const int*)d_in[3];
    const float* ea_h    = (const float*)d_in[4];
    const int*   ei_in   = (const int*)d_in[5];
    const int*   ei_ss   = (const int*)d_in[6];
    const float* tag1_W  = (const float*)d_in[7];
    const float* tag1_b  = (const float*)d_in[8];
    const float* tag2_W  = (const float*)d_in[9];
    const float* tag2_b  = (const float*)d_in[10];
    const float* gc_Wrel = (const float*)d_in[11];
    const float* gc_b    = (const float*)d_in[12];
    const float* gc_Wroot= (const float*)d_in[13];
    const float* sage_Wl = (const float*)d_in[14];
    const float* sage_bl = (const float*)d_in[15];
    const float* sage_Wr = (const float*)d_in[16];
    const float* lin_W   = (const float*)d_in[17];
    const float* lin_b   = (const float*)d_in[18];

    const int NV  = in_sizes[0] / 5;
    const int NS  = in_sizes[1] / 6;
    const int EVV = in_sizes[2] / 2;
    const int EH  = in_sizes[3] / 2;
    const int EIN = in_sizes[5] / 2;
    const int ESS = in_sizes[6] / 2;

    const int *vv_s = ei_vv,  *vv_d = ei_vv + EVV;
    const int *h_s  = ei_h,   *h_d  = ei_h  + EH;
    const int *in_s = ei_in,  *in_d = ei_in + EIN;
    const int *ss_s = ei_ss,  *ss_d = ei_ss + ESS;

    // bin geometry
    const int ncv = (EVV + ACH - 1) / ACH;
    const int nch = (EH  + ACH - 1) / ACH;
    const int nci = (EIN + ACH - 1) / ACH;
    const int ncs = (ESS + ACH - 1) / ACH;
    const int nbv_ = (NV + 255) >> 8;
    const int nbs_ = (NS + 127) >> 7;
    const int Lv = nbv_ * ncv, Lh = nbs_ * nch, Li = nbs_ * nci, Ls = nbs_ * ncs;
    const int nB0 = (Lv + 255) / 256, nB1 = (Lh + 255) / 256,
              nB2 = (Li + 255) / 256, nB3 = (Ls + 255) / 256;

    // ---------------- workspace layout (4-byte words; ws >= 256 MiB) ---------
    float* wsf = (float*)d_ws;
    size_t o = 0;
    unsigned short* gx_bf = (unsigned short*)(wsf + o);   // NV x 64 bf16
    o += (size_t)NV * 32;
    float* B1 = wsf + o; o += (size_t)NS * 64;            // binned vv|in|ss | aggH | hA_bf
    float* B2 = wsf + o; o += (size_t)NS * 64;            // binned h | aggI(ssum) | hB_bf
    float* B4 = wsf + o; o += (size_t)NS * 32;            // H1+H2 packets (NV*16) | sx2_bf
    float* B5 = wsf + o; o += (size_t)NS * 32;            // P0 packets (NV*8) | hC_bf
    float* sxF = wsf + o; o += (size_t)NS * 64;           // fp32 sx (gc out, sage in)
    int*  vvsrc = (int*)(wsf + o); o += (size_t)EVV;
    int*  sssrc = (int*)(wsf + o); o += (size_t)ESS;
    int*  insrc = (int*)(wsf + o); o += (size_t)EIN;
    int2* hsw   = (int2*)(wsf + o); o += (size_t)EH * 2;
    int* T_all = (int*)(wsf + o); o += (size_t)(Lv + Lh + Li + Ls);
    int* bsum  = (int*)(wsf + o); o += 2048;
    int* rv = (int*)(wsf + o); o += (size_t)NV + 1;
    int* rh = (int*)(wsf + o); o += (size_t)NS + 1;
    int* ri = (int*)(wsf + o); o += (size_t)NS + 1;
    int* rs = (int*)(wsf + o); o += (size_t)NS + 1;
    float* dinv_s = wsf + o; o += (size_t)NS;

    int* Tv = T_all;
    int* Th = Tv + Lv;
    int* Ti = Th + Lh;
    int* Ts = Ti + Li;

    // phase-0 binned edge buffers alias B1/B2 (dead until stage B)
    unsigned* vvbin = (unsigned*)B1;
    unsigned* inbin = vvbin + EVV;
    unsigned* ssbin = inbin + EIN;
    int2* hbin = (int2*)B2;

    unsigned short* hA_bf  = (unsigned short*)B1;
    unsigned short* hB_bf  = (unsigned short*)B2;
    unsigned short* hC_bf  = (unsigned short*)B5;
    unsigned short* sx2_bf = (unsigned short*)B4;
    float* P0 = B5;                         // packed (x,dinv) NV*8 floats
    float* H1 = B4;                         // packed hop-1     NV*8 floats
    float* H2 = B4 + (size_t)NV * 8;        // packed hop-2     NV*8 floats

    // ================= Phase 0: atomic-free batched CSR build =================
    int nbins   = nbv_ + 3 * nbs_;
    int nBtot   = nB0 + nB1 + nB2 + nB3;
    k_binA1<<<ncv + nch + nci + ncs, 256, 0, stream>>>(vv_d, h_d, in_d, ss_d, Tv, Th, Ti, Ts,
                                         ncv, nch, nci, ncs, nbv_, nbs_,
                                         EVV, EH, EIN, ESS);
    k_sb2<<<nBtot, 256, 0, stream>>>(T_all, bsum, Lv, Lh, Li, Ls, nB0, nB1, nB2, nB3);
    k_st2<<<4, 1024, 0, stream>>>(bsum, nB0, nB1, nB2, nB3);
    k_sa2<<<nBtot, 256, 0, stream>>>(T_all, bsum, Lv, Lh, Li, Ls, nB0, nB1, nB2, nB3);
    k_binA2a<<<ncv + nci + ncs, 512, 0, stream>>>(vv_s, vv_d, in_s, in_d, ss_s, ss_d,
                                                  Tv, Ti, Ts, vvbin, inbin, ssbin,
                                                  ncv, nci, ncs, nbv_, nbs_,
                                                  EVV, EIN, ESS);
    k_binA2h<<<nch, 512, 0, stream>>>(h_s, h_d, ea_h, Th, hbin, nch, nbs_, EH);
    k_binB<<<nbins, 256, 0, stream>>>(vvbin, hbin, inbin, ssbin,
                                      Tv, Th, Ti, Ts,
                                      rv, rh, ri, rs,
                                      game_x, P0, dinv_s,
                                      vvsrc, hsw, insrc, sssrc,
                                      ncv, nch, nci, ncs, nbv_, nbs_,
                                      NV, NS, EVV, EH, EIN, ESS);

    // ================= Stage A: TAGConv1 on v-v (packet form) =================
    k_gather5p<<<gblk(NV), BLK, 0, stream>>>(P0, rv, vvsrc, H1, NV);
    k_gather5p<<<gblk(NV), BLK, 0, stream>>>(H1, rv, vvsrc, H2, NV);
    k_tag1_w<<<gwv4(NV), BLK, 0, stream>>>(game_x, H1, H2, tag1_W, tag1_b, gx_bf, NV);

    // ====== Stage B+C: fused h-graph (weighted) + in-graph (plain) gather =====
    k_gatherBC<<<gblk(2LL * NS * 64), BLK, 0, stream>>>(gx_bf, rh, hsw, ri, insrc,
                                                        B1, B2, NS);
    // split dense combines (no LDS, no bank conflicts)
    k_gc_mf<<<gw32(NS), BLK, 0, stream>>>(B1, state_x, gc_Wrel, gc_Wroot, gc_b, sxF, NS);
    k_sage_mf<<<gw32(NS), BLK, 0, stream>>>(B2, ri, sxF, sage_Wl, sage_Wr, sage_bl, sx2_bf, NS);

    // ================= Stage D: TAGConv2 hops (gathers only), then fused dense
    k_gather64<2, true><<<gblk((long long)NS * 64), BLK, 0, stream>>>(sx2_bf, rs, sssrc, nullptr, dinv_s, hA_bf, NS);
    k_gather64<2, true><<<gblk((long long)NS * 64), BLK, 0, stream>>>(hA_bf, rs, sssrc, nullptr, dinv_s, hB_bf, NS);
    k_gather64<2, true><<<gblk((long long)NS * 64), BLK, 0, stream>>>(hB_bf, rs, sssrc, nullptr, dinv_s, hC_bf, NS);
    k_tagmm<<<gw32(NS), BLK, 0, stream>>>(sx2_bf, hA_bf, hB_bf, hC_bf,
                                          tag2_W, tag2_b, lin_W, lin_b,
                                          (float*)d_out, NS);
}